// Round 1
// baseline (1884.070 us; speedup 1.0000x reference)
//
#include <hip/hip_runtime.h>
#include <hip/hip_bf16.h>

// Problem constants
#define BB 2
#define SS 1024
#define DD 768
#define HH 12
#define HD 64
#define DFF 3072
#define EPS 1e-5f

// ---------------------------------------------------------------------------
// LayerNorm: one block per row (B*S rows), 256 threads, D=768
// ---------------------------------------------------------------------------
__global__ __launch_bounds__(256) void ln_kernel(
    const float* __restrict__ x, const float* __restrict__ g,
    const float* __restrict__ b, float* __restrict__ y)
{
    const int row = blockIdx.x;
    const float* xr = x + (size_t)row * DD;
    float s = 0.f, ss = 0.f;
    for (int i = threadIdx.x; i < DD; i += 256) {
        float v = xr[i];
        s += v; ss += v * v;
    }
    // wave64 reduce
    for (int off = 32; off; off >>= 1) {
        s  += __shfl_down(s,  off);
        ss += __shfl_down(ss, off);
    }
    __shared__ float reds[4], redss[4], bc[2];
    int t = threadIdx.x;
    if ((t & 63) == 0) { reds[t >> 6] = s; redss[t >> 6] = ss; }
    __syncthreads();
    if (t == 0) {
        float S1 = reds[0] + reds[1] + reds[2] + reds[3];
        float S2 = redss[0] + redss[1] + redss[2] + redss[3];
        float mean = S1 / DD;
        float var = S2 / DD - mean * mean;
        bc[0] = mean;
        bc[1] = rsqrtf(var + EPS);
    }
    __syncthreads();
    float mean = bc[0], inv = bc[1];
    float* yr = y + (size_t)row * DD;
    for (int i = threadIdx.x; i < DD; i += 256) {
        yr[i] = (xr[i] - mean) * inv * g[i] + b[i];
    }
}

// ---------------------------------------------------------------------------
// C[M,N] = act( A[M,K] @ W[N,K]^T + bias + resid )
// 64x64 tile, BK=16, 256 threads, 4x4 micro-tile per thread.
// M,N divisible by 64; K divisible by 16 (and by 4 for float4 loads).
// ---------------------------------------------------------------------------
#define BM 64
#define BN 64
#define BK 16

template <bool RELU>
__global__ __launch_bounds__(256) void gemm_wt(
    const float* __restrict__ A, const float* __restrict__ W,
    const float* __restrict__ bias, const float* __restrict__ resid,
    float* __restrict__ C, int M, int N, int K)
{
    __shared__ float As[BK][BM + 1];
    __shared__ float Ws[BK][BN + 1];

    const int t  = threadIdx.x;
    const int tx = t & 15;
    const int ty = t >> 4;
    const int m0 = blockIdx.y * BM;
    const int n0 = blockIdx.x * BN;

    const int lrow = t >> 2;        // 0..63
    const int lkk  = (t & 3) * 4;   // 0,4,8,12

    float acc[4][4] = {};

    for (int k0 = 0; k0 < K; k0 += BK) {
        // load A tile (64 x 16) and W tile (64 x 16), float4 per thread
        const float4 a4 = *reinterpret_cast<const float4*>(
            A + (size_t)(m0 + lrow) * K + k0 + lkk);
        const float4 w4 = *reinterpret_cast<const float4*>(
            W + (size_t)(n0 + lrow) * K + k0 + lkk);
        __syncthreads();
        As[lkk + 0][lrow] = a4.x; As[lkk + 1][lrow] = a4.y;
        As[lkk + 2][lrow] = a4.z; As[lkk + 3][lrow] = a4.w;
        Ws[lkk + 0][lrow] = w4.x; Ws[lkk + 1][lrow] = w4.y;
        Ws[lkk + 2][lrow] = w4.z; Ws[lkk + 3][lrow] = w4.w;
        __syncthreads();

#pragma unroll
        for (int k = 0; k < BK; ++k) {
            float a_[4], w_[4];
#pragma unroll
            for (int i = 0; i < 4; ++i) a_[i] = As[k][ty * 4 + i];
#pragma unroll
            for (int j = 0; j < 4; ++j) w_[j] = Ws[k][tx * 4 + j];
#pragma unroll
            for (int i = 0; i < 4; ++i)
#pragma unroll
                for (int j = 0; j < 4; ++j)
                    acc[i][j] += a_[i] * w_[j];
        }
    }

#pragma unroll
    for (int i = 0; i < 4; ++i) {
        const int m = m0 + ty * 4 + i;
#pragma unroll
        for (int j = 0; j < 4; ++j) {
            const int n = n0 + tx * 4 + j;
            float v = acc[i][j];
            if (bias)  v += bias[n];
            if (resid) v += resid[(size_t)m * N + n];
            if (RELU)  v = fmaxf(v, 0.f);
            C[(size_t)m * N + n] = v;
        }
    }
}

// ---------------------------------------------------------------------------
// Attention: one block per (b, h, q). 256 threads.
// qkv layout: (B, S, 3*D); q at col [0,768), k at [768,1536), v at [1536,2304),
// head h occupies cols h*64..h*64+63 within each third.
// ---------------------------------------------------------------------------
__global__ __launch_bounds__(256) void attn_kernel(
    const float* __restrict__ qkv, const int* __restrict__ rel_matrix,
    const unsigned char* __restrict__ mask, const float* __restrict__ rel_A,
    float* __restrict__ attnout)
{
    const int bid = blockIdx.x;
    const int q = bid & (SS - 1);
    const int h = (bid >> 10) % HH;
    const int b = bid / (SS * HH);
    const int t = threadIdx.x;

    __shared__ float qv[HD];
    __shared__ float r3[3];
    __shared__ float lg[SS];
    __shared__ float red[8];
    __shared__ float part[4][HD];

    const float* qrow = qkv + (size_t)(b * SS + q) * (3 * DD) + h * HD;
    if (t < HD) qv[t] = qrow[t];
    __syncthreads();
    if (t < 3) {
        float r = 0.f;
        for (int d = 0; d < HD; ++d) r += qv[d] * rel_A[t * HD + d];
        r3[t] = r;
    }
    __syncthreads();

    const int* relrow = rel_matrix + ((size_t)b * SS + q) * SS;
    const unsigned char* mrow = mask + (size_t)b * SS;
    float lmax = -1e30f;
    for (int k = t; k < SS; k += 256) {
        const float* krow = qkv + (size_t)(b * SS + k) * (3 * DD) + DD + h * HD;
        float dot = 0.f;
#pragma unroll
        for (int d = 0; d < HD; ++d) dot += qv[d] * krow[d];
        float lv = (dot + r3[relrow[k] + 1]) * 0.125f;
        if (mrow[k]) lv = -1e30f;
        lg[k] = lv;
        lmax = fmaxf(lmax, lv);
    }
    for (int off = 32; off; off >>= 1) lmax = fmaxf(lmax, __shfl_down(lmax, off));
    if ((t & 63) == 0) red[t >> 6] = lmax;
    __syncthreads();
    if (t == 0)
        red[4] = fmaxf(fmaxf(red[0], red[1]), fmaxf(red[2], red[3]));
    __syncthreads();
    const float m = red[4];

    float lsum = 0.f;
    for (int k = t; k < SS; k += 256) {
        float p = __expf(lg[k] - m);
        lg[k] = p;
        lsum += p;
    }
    for (int off = 32; off; off >>= 1) lsum += __shfl_down(lsum, off);
    if ((t & 63) == 0) red[t >> 6] = lsum;
    __syncthreads();
    if (t == 0) red[4] = 1.0f / (red[0] + red[1] + red[2] + red[3]);
    __syncthreads();
    const float inv = red[4];

    // out[d] = sum_k p[k] * V[k][d], split k into 4 chunks of 256
    const int d = t & 63, ch = t >> 6;
    float acc = 0.f;
    const int kbeg = ch * 256, kend = kbeg + 256;
    for (int k = kbeg; k < kend; ++k) {
        const float* vrow = qkv + (size_t)(b * SS + k) * (3 * DD) + 2 * DD + h * HD;
        acc += lg[k] * vrow[d];
    }
    part[ch][d] = acc;
    __syncthreads();
    if (t < HD) {
        float o = (part[0][t] + part[1][t] + part[2][t] + part[3][t]) * inv;
        attnout[(size_t)(b * SS + q) * DD + h * HD + t] = o;
    }
}

// ---------------------------------------------------------------------------
extern "C" void kernel_launch(void* const* d_in, const int* in_sizes, int n_in,
                              void* d_out, int out_size, void* d_ws, size_t ws_size,
                              hipStream_t stream) {
    const float* inp   = (const float*)d_in[0];
    const unsigned char* amask = (const unsigned char*)d_in[1];
    const int*   relm  = (const int*)d_in[2];
    const float* qkv_w = (const float*)d_in[3];
    const float* rel_A = (const float*)d_in[4];
    const float* o_w   = (const float*)d_in[5];
    const float* w1    = (const float*)d_in[6];
    const float* b1    = (const float*)d_in[7];
    const float* w2    = (const float*)d_in[8];
    const float* b2    = (const float*)d_in[9];
    const float* ln1_g = (const float*)d_in[10];
    const float* ln1_b = (const float*)d_in[11];
    const float* ln2_g = (const float*)d_in[12];
    const float* ln2_b = (const float*)d_in[13];
    float* out = (float*)d_out;

    const int BS = BB * SS;  // 2048 rows

    float* ws    = (float*)d_ws;
    float* x     = ws;                       // (BS, D)      ln1 out
    float* qkvb  = x     + (size_t)BS * DD;  // (BS, 3D)
    float* att   = qkvb  + (size_t)BS * 3 * DD; // (BS, D)   attention out
    float* resid = att   + (size_t)BS * DD;  // (BS, D)      inp + attn@o_w.T
    float* hbuf  = resid + (size_t)BS * DD;  // (BS, D)      ln2 out
    float* ff    = hbuf  + (size_t)BS * DD;  // (BS, DFF)    relu(mlp1)

    // 1. LN1
    ln_kernel<<<BS, 256, 0, stream>>>(inp, ln1_g, ln1_b, x);

    // 2. QKV = x @ qkv_w.T   (2048 x 2304 x 768)
    gemm_wt<false><<<dim3(3 * DD / BN, BS / BM), 256, 0, stream>>>(
        x, qkv_w, nullptr, nullptr, qkvb, BS, 3 * DD, DD);

    // 3. Attention
    attn_kernel<<<BB * HH * SS, 256, 0, stream>>>(qkvb, relm, amask, rel_A, att);

    // 4. resid = inp + att @ o_w.T   (2048 x 768 x 768)
    gemm_wt<false><<<dim3(DD / BN, BS / BM), 256, 0, stream>>>(
        att, o_w, nullptr, inp, resid, BS, DD, DD);

    // 5. LN2
    ln_kernel<<<BS, 256, 0, stream>>>(resid, ln2_g, ln2_b, hbuf);

    // 6. ff = relu(h @ w1.T + b1)   (2048 x 3072 x 768)
    gemm_wt<true><<<dim3(DFF / BN, BS / BM), 256, 0, stream>>>(
        hbuf, w1, b1, nullptr, ff, BS, DFF, DD);

    // 7. out = resid + ff @ w2.T + b2   (2048 x 768 x 3072)
    gemm_wt<false><<<dim3(DD / BN, BS / BM), 256, 0, stream>>>(
        ff, w2, b2, resid, out, BS, DD, DFF);
}

// Round 2
// 956.372 us; speedup vs baseline: 1.9700x; 1.9700x over previous
//
#include <hip/hip_runtime.h>
#include <hip/hip_bf16.h>

// Problem constants
#define BB 2
#define SS 1024
#define DD 768
#define HH 12
#define HD 64
#define DFF 3072
#define EPS 1e-5f

// ---------------------------------------------------------------------------
// LayerNorm: one block per row (B*S rows), 256 threads, D=768
// ---------------------------------------------------------------------------
__global__ __launch_bounds__(256) void ln_kernel(
    const float* __restrict__ x, const float* __restrict__ g,
    const float* __restrict__ b, float* __restrict__ y)
{
    const int row = blockIdx.x;
    const float* xr = x + (size_t)row * DD;
    float s = 0.f, ss = 0.f;
    for (int i = threadIdx.x; i < DD; i += 256) {
        float v = xr[i];
        s += v; ss += v * v;
    }
    for (int off = 32; off; off >>= 1) {
        s  += __shfl_down(s,  off);
        ss += __shfl_down(ss, off);
    }
    __shared__ float reds[4], redss[4], bc[2];
    int t = threadIdx.x;
    if ((t & 63) == 0) { reds[t >> 6] = s; redss[t >> 6] = ss; }
    __syncthreads();
    if (t == 0) {
        float S1 = reds[0] + reds[1] + reds[2] + reds[3];
        float S2 = redss[0] + redss[1] + redss[2] + redss[3];
        float mean = S1 / DD;
        float var = S2 / DD - mean * mean;
        bc[0] = mean;
        bc[1] = rsqrtf(var + EPS);
    }
    __syncthreads();
    float mean = bc[0], inv = bc[1];
    float* yr = y + (size_t)row * DD;
    for (int i = threadIdx.x; i < DD; i += 256) {
        yr[i] = (xr[i] - mean) * inv * g[i] + b[i];
    }
}

// ---------------------------------------------------------------------------
// C[M,N] = act( A[M,K] @ W[N,K]^T + bias + resid )
// 64x64 tile, BK=16, 256 threads, 4x4 micro-tile per thread.
// ---------------------------------------------------------------------------
#define BM 64
#define BN 64
#define BK 16

template <bool RELU>
__global__ __launch_bounds__(256) void gemm_wt(
    const float* __restrict__ A, const float* __restrict__ W,
    const float* __restrict__ bias, const float* __restrict__ resid,
    float* __restrict__ C, int M, int N, int K)
{
    __shared__ float As[BK][BM + 1];
    __shared__ float Ws[BK][BN + 1];

    const int t  = threadIdx.x;
    const int tx = t & 15;
    const int ty = t >> 4;
    const int m0 = blockIdx.y * BM;
    const int n0 = blockIdx.x * BN;

    const int lrow = t >> 2;        // 0..63
    const int lkk  = (t & 3) * 4;   // 0,4,8,12

    float acc[4][4] = {};

    for (int k0 = 0; k0 < K; k0 += BK) {
        const float4 a4 = *reinterpret_cast<const float4*>(
            A + (size_t)(m0 + lrow) * K + k0 + lkk);
        const float4 w4 = *reinterpret_cast<const float4*>(
            W + (size_t)(n0 + lrow) * K + k0 + lkk);
        __syncthreads();
        As[lkk + 0][lrow] = a4.x; As[lkk + 1][lrow] = a4.y;
        As[lkk + 2][lrow] = a4.z; As[lkk + 3][lrow] = a4.w;
        Ws[lkk + 0][lrow] = w4.x; Ws[lkk + 1][lrow] = w4.y;
        Ws[lkk + 2][lrow] = w4.z; Ws[lkk + 3][lrow] = w4.w;
        __syncthreads();

#pragma unroll
        for (int k = 0; k < BK; ++k) {
            float a_[4], w_[4];
#pragma unroll
            for (int i = 0; i < 4; ++i) a_[i] = As[k][ty * 4 + i];
#pragma unroll
            for (int j = 0; j < 4; ++j) w_[j] = Ws[k][tx * 4 + j];
#pragma unroll
            for (int i = 0; i < 4; ++i)
#pragma unroll
                for (int j = 0; j < 4; ++j)
                    acc[i][j] += a_[i] * w_[j];
        }
    }

#pragma unroll
    for (int i = 0; i < 4; ++i) {
        const int m = m0 + ty * 4 + i;
#pragma unroll
        for (int j = 0; j < 4; ++j) {
            const int n = n0 + tx * 4 + j;
            float v = acc[i][j];
            if (bias)  v += bias[n];
            if (resid) v += resid[(size_t)m * N + n];
            if (RELU)  v = fmaxf(v, 0.f);
            C[(size_t)m * N + n] = v;
        }
    }
}

// ---------------------------------------------------------------------------
// Flash-style tiled attention.
// One block per (b, h, 32-query tile). 256 threads = 16 (tq) x 16 (tk).
// Per-thread micro-tile: q in {tq, tq+16}, k in {tk, tk+16, tk+32, tk+48}.
// K/V staged in LDS 64 rows at a time; online softmax; P@V accumulated in regs.
// LDS row stride 68 floats (= 17 float4 granules, odd) -> no serious conflicts.
// ---------------------------------------------------------------------------
#define QT 32
#define KTT 64
#define LSTR 68

__global__ __launch_bounds__(256) void attn_tile_kernel(
    const float* __restrict__ qkv, const int* __restrict__ rel_matrix,
    const unsigned char* __restrict__ mask, const float* __restrict__ rel_A,
    float* __restrict__ attnout)
{
    __shared__ float Qs[QT * LSTR];
    __shared__ float Ks[KTT * LSTR];
    __shared__ float Vs[KTT * LSTR];
    __shared__ float Ps[QT * LSTR];
    __shared__ float r3s[QT][4];

    const int bx = blockIdx.x;
    const int qt = bx & 31;            // S/QT = 32 tiles
    const int h  = (bx >> 5) % HH;
    const int b  = bx / (32 * HH);
    const int q0 = qt * QT;
    const int t  = threadIdx.x;
    const int tq = t >> 4;   // 0..15
    const int tk = t & 15;   // 0..15

    // --- stage Q tile (32 x 64) ---
    {
        const int r = t >> 3;            // 0..31
        const int c = (t & 7) * 8;       // 0,8,...,56
        const float* src = qkv + (size_t)(b * SS + q0 + r) * (3 * DD) + h * HD + c;
        float4 v0 = *(const float4*)(src);
        float4 v1 = *(const float4*)(src + 4);
        *(float4*)&Qs[r * LSTR + c]     = v0;
        *(float4*)&Qs[r * LSTR + c + 4] = v1;
    }
    __syncthreads();
    // --- r3[q][c] = q_row . rel_A[c] ---
    if (t < 128) {
        int q = t >> 2, c = t & 3;
        if (c < 3) {
            float s = 0.f;
            const float* a = rel_A + c * HD;
            for (int d = 0; d < HD; ++d) s += Qs[q * LSTR + d] * a[d];
            r3s[q][c] = s;
        }
    }

    float m_run[2] = {-1e30f, -1e30f};
    float l_run[2] = {0.f, 0.f};
    float oacc[2][4] = {};

    const int* relbase = rel_matrix + (size_t)b * SS * SS;
    const unsigned char* mrow = mask + (size_t)b * SS;

    for (int k0 = 0; k0 < SS; k0 += KTT) {
        __syncthreads();
        // stage K (64x64) and V (64x64)
        {
            const int r = t >> 2;                  // 0..63
            const int cb = (t & 3) * 16;           // 0,16,32,48
            const float* kr = qkv + (size_t)(b * SS + k0 + r) * (3 * DD) + DD + h * HD + cb;
            const float* vr = kr + DD;
            float4 ka = ((const float4*)kr)[0];
            float4 kb = ((const float4*)kr)[1];
            float4 kc = ((const float4*)kr)[2];
            float4 kd = ((const float4*)kr)[3];
            float4 va = ((const float4*)vr)[0];
            float4 vb = ((const float4*)vr)[1];
            float4 vc = ((const float4*)vr)[2];
            float4 vd = ((const float4*)vr)[3];
            float* kdst = &Ks[r * LSTR + cb];
            float* vdst = &Vs[r * LSTR + cb];
            ((float4*)kdst)[0] = ka; ((float4*)kdst)[1] = kb;
            ((float4*)kdst)[2] = kc; ((float4*)kdst)[3] = kd;
            ((float4*)vdst)[0] = va; ((float4*)vdst)[1] = vb;
            ((float4*)vdst)[2] = vc; ((float4*)vdst)[3] = vd;
        }
        __syncthreads();

        // S = Q @ K^T micro-tile
        float s_[2][4] = {};
#pragma unroll
        for (int d4 = 0; d4 < HD; d4 += 4) {
            float4 qa = *(const float4*)&Qs[tq * LSTR + d4];
            float4 qb = *(const float4*)&Qs[(tq + 16) * LSTR + d4];
#pragma unroll
            for (int jj = 0; jj < 4; ++jj) {
                float4 kv = *(const float4*)&Ks[(tk + 16 * jj) * LSTR + d4];
                s_[0][jj] += qa.x * kv.x + qa.y * kv.y + qa.z * kv.z + qa.w * kv.w;
                s_[1][jj] += qb.x * kv.x + qb.y * kv.y + qb.z * kv.z + qb.w * kv.w;
            }
        }

        // rel gather + mask + scale
#pragma unroll
        for (int ql = 0; ql < 2; ++ql) {
            const int q = tq + 16 * ql;
            const int* relrow = relbase + (size_t)(q0 + q) * SS + k0;
#pragma unroll
            for (int jj = 0; jj < 4; ++jj) {
                const int k = tk + 16 * jj;
                int idx = relrow[k] + 1;
                float lv = (s_[ql][jj] + r3s[q][idx]) * 0.125f;
                if (mrow[k0 + k]) lv = -3e30f;
                s_[ql][jj] = lv;
            }
        }

        // online softmax (row groups are the 16 tk-lanes sharing a tq)
#pragma unroll
        for (int ql = 0; ql < 2; ++ql) {
            float tm = fmaxf(fmaxf(s_[ql][0], s_[ql][1]), fmaxf(s_[ql][2], s_[ql][3]));
            tm = fmaxf(tm, __shfl_xor(tm, 1));
            tm = fmaxf(tm, __shfl_xor(tm, 2));
            tm = fmaxf(tm, __shfl_xor(tm, 4));
            tm = fmaxf(tm, __shfl_xor(tm, 8));
            float mn = fmaxf(m_run[ql], tm);
            float alpha = __expf(m_run[ql] - mn);
            m_run[ql] = mn;
            float ts = 0.f;
#pragma unroll
            for (int jj = 0; jj < 4; ++jj) {
                float p = __expf(s_[ql][jj] - mn);
                s_[ql][jj] = p;
                ts += p;
            }
            ts += __shfl_xor(ts, 1);
            ts += __shfl_xor(ts, 2);
            ts += __shfl_xor(ts, 4);
            ts += __shfl_xor(ts, 8);
            l_run[ql] = l_run[ql] * alpha + ts;
#pragma unroll
            for (int j = 0; j < 4; ++j) oacc[ql][j] *= alpha;
            const int q = tq + 16 * ql;
#pragma unroll
            for (int jj = 0; jj < 4; ++jj)
                Ps[q * LSTR + tk + 16 * jj] = s_[ql][jj];
        }
        __syncthreads();

        // O += P @ V : per-thread d columns 4*tk..4*tk+3
#pragma unroll
        for (int kk = 0; kk < KTT; kk += 4) {
            float4 pa = *(const float4*)&Ps[tq * LSTR + kk];
            float4 pb = *(const float4*)&Ps[(tq + 16) * LSTR + kk];
            float pav[4] = {pa.x, pa.y, pa.z, pa.w};
            float pbv[4] = {pb.x, pb.y, pb.z, pb.w};
#pragma unroll
            for (int i = 0; i < 4; ++i) {
                float4 vv = *(const float4*)&Vs[(kk + i) * LSTR + 4 * tk];
                oacc[0][0] += pav[i] * vv.x;
                oacc[0][1] += pav[i] * vv.y;
                oacc[0][2] += pav[i] * vv.z;
                oacc[0][3] += pav[i] * vv.w;
                oacc[1][0] += pbv[i] * vv.x;
                oacc[1][1] += pbv[i] * vv.y;
                oacc[1][2] += pbv[i] * vv.z;
                oacc[1][3] += pbv[i] * vv.w;
            }
        }
    }

    // epilogue
#pragma unroll
    for (int ql = 0; ql < 2; ++ql) {
        const int q = q0 + tq + 16 * ql;
        float inv = 1.0f / l_run[ql];
        float4 o;
        o.x = oacc[ql][0] * inv;
        o.y = oacc[ql][1] * inv;
        o.z = oacc[ql][2] * inv;
        o.w = oacc[ql][3] * inv;
        *(float4*)&attnout[(size_t)(b * SS + q) * DD + h * HD + 4 * tk] = o;
    }
}

// ---------------------------------------------------------------------------
extern "C" void kernel_launch(void* const* d_in, const int* in_sizes, int n_in,
                              void* d_out, int out_size, void* d_ws, size_t ws_size,
                              hipStream_t stream) {
    const float* inp   = (const float*)d_in[0];
    const unsigned char* amask = (const unsigned char*)d_in[1];
    const int*   relm  = (const int*)d_in[2];
    const float* qkv_w = (const float*)d_in[3];
    const float* rel_A = (const float*)d_in[4];
    const float* o_w   = (const float*)d_in[5];
    const float* w1    = (const float*)d_in[6];
    const float* b1    = (const float*)d_in[7];
    const float* w2    = (const float*)d_in[8];
    const float* b2    = (const float*)d_in[9];
    const float* ln1_g = (const float*)d_in[10];
    const float* ln1_b = (const float*)d_in[11];
    const float* ln2_g = (const float*)d_in[12];
    const float* ln2_b = (const float*)d_in[13];
    float* out = (float*)d_out;

    const int BS = BB * SS;  // 2048 rows

    float* ws    = (float*)d_ws;
    float* x     = ws;                          // (BS, D)
    float* qkvb  = x     + (size_t)BS * DD;     // (BS, 3D)
    float* att   = qkvb  + (size_t)BS * 3 * DD; // (BS, D)
    float* resid = att   + (size_t)BS * DD;     // (BS, D)
    float* hbuf  = resid + (size_t)BS * DD;     // (BS, D)
    float* ff    = hbuf  + (size_t)BS * DD;     // (BS, DFF)

    // 1. LN1
    ln_kernel<<<BS, 256, 0, stream>>>(inp, ln1_g, ln1_b, x);

    // 2. QKV = x @ qkv_w.T
    gemm_wt<false><<<dim3(3 * DD / BN, BS / BM), 256, 0, stream>>>(
        x, qkv_w, nullptr, nullptr, qkvb, BS, 3 * DD, DD);

    // 3. Attention (flash-style tiles): grid = B*H*(S/QT) = 2*12*32 = 768
    attn_tile_kernel<<<BB * HH * (SS / QT), 256, 0, stream>>>(
        qkvb, relm, amask, rel_A, att);

    // 4. resid = inp + att @ o_w.T
    gemm_wt<false><<<dim3(DD / BN, BS / BM), 256, 0, stream>>>(
        att, o_w, nullptr, inp, resid, BS, DD, DD);

    // 5. LN2
    ln_kernel<<<BS, 256, 0, stream>>>(resid, ln2_g, ln2_b, hbuf);

    // 6. ff = relu(h @ w1.T + b1)
    gemm_wt<true><<<dim3(DFF / BN, BS / BM), 256, 0, stream>>>(
        hbuf, w1, b1, nullptr, ff, BS, DFF, DD);

    // 7. out = resid + ff @ w2.T + b2
    gemm_wt<false><<<dim3(DD / BN, BS / BM), 256, 0, stream>>>(
        ff, w2, b2, resid, out, BS, DD, DFF);
}

// Round 3
// 467.286 us; speedup vs baseline: 4.0319x; 2.0467x over previous
//
#include <hip/hip_runtime.h>
#include <hip/hip_bf16.h>

// Problem constants
#define BB 2
#define SS 1024
#define DD 768
#define HH 12
#define HD 64
#define DFF 3072
#define EPS 1e-5f

typedef unsigned short ushort_t;
using short8 = __attribute__((ext_vector_type(8))) short;
using f32x4  = __attribute__((ext_vector_type(4))) float;

__device__ __forceinline__ ushort_t f2bf_rne(float f) {
    union { float f; unsigned u; } x; x.f = f;
    unsigned r = x.u + 0x7fff + ((x.u >> 16) & 1);
    return (ushort_t)(r >> 16);
}

// ---------------------------------------------------------------------------
// fp32 -> bf16 conversion (vectorized), n4 = n/4
// ---------------------------------------------------------------------------
__global__ __launch_bounds__(256) void cvt_bf16(
    const float* __restrict__ in, ushort_t* __restrict__ out, int n4)
{
    int i = blockIdx.x * 256 + threadIdx.x;
    if (i < n4) {
        float4 v = ((const float4*)in)[i];
        ushort4 o;
        o.x = f2bf_rne(v.x); o.y = f2bf_rne(v.y);
        o.z = f2bf_rne(v.z); o.w = f2bf_rne(v.w);
        ((ushort4*)out)[i] = o;
    }
}

// ---------------------------------------------------------------------------
// LayerNorm: fp32 in -> bf16 out. One block per row, 256 threads, D=768.
// ---------------------------------------------------------------------------
__global__ __launch_bounds__(256) void ln_kernel_bf(
    const float* __restrict__ x, const float* __restrict__ g,
    const float* __restrict__ b, ushort_t* __restrict__ y)
{
    const int row = blockIdx.x;
    const float* xr = x + (size_t)row * DD;
    float s = 0.f, ss = 0.f;
    for (int i = threadIdx.x; i < DD; i += 256) {
        float v = xr[i];
        s += v; ss += v * v;
    }
    for (int off = 32; off; off >>= 1) {
        s  += __shfl_down(s,  off);
        ss += __shfl_down(ss, off);
    }
    __shared__ float reds[4], redss[4], bc[2];
    int t = threadIdx.x;
    if ((t & 63) == 0) { reds[t >> 6] = s; redss[t >> 6] = ss; }
    __syncthreads();
    if (t == 0) {
        float S1 = reds[0] + reds[1] + reds[2] + reds[3];
        float S2 = redss[0] + redss[1] + redss[2] + redss[3];
        float mean = S1 / DD;
        float var = S2 / DD - mean * mean;
        bc[0] = mean;
        bc[1] = rsqrtf(var + EPS);
    }
    __syncthreads();
    float mean = bc[0], inv = bc[1];
    ushort_t* yr = y + (size_t)row * DD;
    for (int i = threadIdx.x; i < DD; i += 256) {
        yr[i] = f2bf_rne((xr[i] - mean) * inv * g[i] + b[i]);
    }
}

// ---------------------------------------------------------------------------
// bf16 MFMA GEMM: C[M,N] = act( A[M,K](bf16) @ W[N,K](bf16)^T + bias + resid )
// 128x128 tile, BK=32, 256 threads = 4 waves, each wave 4x4 of 16x16x32 MFMA.
// LDS chunk layout: slot s = khalf*128 + row  (khalf = k/8), 8 bf16 per slot.
//   -> global_load_lds width=16 staging (lds = wave-uniform base + lane*16)
//   -> fragment ds_read_b128 conflict-free (lanes 0..15 read consecutive slots)
// ---------------------------------------------------------------------------
#define GTM 128
#define GTN 128
#define GTK 32

template <bool RELU, bool OUT_BF16, bool HAS_BIAS, bool HAS_RES>
__global__ __launch_bounds__(256) void gemm_mfma(
    const ushort_t* __restrict__ A, const ushort_t* __restrict__ W,
    const float* __restrict__ bias, const float* __restrict__ resid,
    void* __restrict__ Cout, int M, int N, int K)
{
    __shared__ __align__(16) ushort_t As[512 * 8];   // 8 KB
    __shared__ __align__(16) ushort_t Bs[512 * 8];   // 8 KB

    const int t  = threadIdx.x;
    const int m0 = blockIdx.y * GTM;
    const int n0 = blockIdx.x * GTN;
    const int w  = t >> 6;
    const int l  = t & 63;
    const int wm = (w >> 1) * 64;    // wave row offset in tile
    const int wn = (w & 1) * 64;     // wave col offset in tile
    const int lm = l & 15;
    const int kq = l >> 4;           // khalf 0..3

    // staging: slots s0 = t (khalf 0/1), s1 = t+256 (khalf 2/3)
    const ushort_t* gA0 = A + (size_t)(m0 + (t & 127)) * K + (t >> 7) * 8;
    const ushort_t* gA1 = A + (size_t)(m0 + (t & 127)) * K + ((t >> 7) + 2) * 8;
    const ushort_t* gB0 = W + (size_t)(n0 + (t & 127)) * K + (t >> 7) * 8;
    const ushort_t* gB1 = W + (size_t)(n0 + (t & 127)) * K + ((t >> 7) + 2) * 8;
    ushort_t* lA0 = &As[(size_t)t * 8];
    ushort_t* lA1 = &As[(size_t)(t + 256) * 8];
    ushort_t* lB0 = &Bs[(size_t)t * 8];
    ushort_t* lB1 = &Bs[(size_t)(t + 256) * 8];

    // fragment read pointers (per wave)
    const ushort_t* aptr = &As[(size_t)(kq * 128 + wm + lm) * 8];
    const ushort_t* bptr = &Bs[(size_t)(kq * 128 + wn + lm) * 8];

    f32x4 acc[4][4] = {};

    for (int k0 = 0; k0 < K; k0 += GTK) {
        __syncthreads();
        __builtin_amdgcn_global_load_lds(
            (const __attribute__((address_space(1))) unsigned int*)(gA0 + k0),
            (__attribute__((address_space(3))) unsigned int*)lA0, 16, 0, 0);
        __builtin_amdgcn_global_load_lds(
            (const __attribute__((address_space(1))) unsigned int*)(gA1 + k0),
            (__attribute__((address_space(3))) unsigned int*)lA1, 16, 0, 0);
        __builtin_amdgcn_global_load_lds(
            (const __attribute__((address_space(1))) unsigned int*)(gB0 + k0),
            (__attribute__((address_space(3))) unsigned int*)lB0, 16, 0, 0);
        __builtin_amdgcn_global_load_lds(
            (const __attribute__((address_space(1))) unsigned int*)(gB1 + k0),
            (__attribute__((address_space(3))) unsigned int*)lB1, 16, 0, 0);
        __syncthreads();

        short8 af[4], bf[4];
#pragma unroll
        for (int i = 0; i < 4; ++i)
            af[i] = *(const short8*)(aptr + (size_t)i * 16 * 8);
#pragma unroll
        for (int j = 0; j < 4; ++j)
            bf[j] = *(const short8*)(bptr + (size_t)j * 16 * 8);
#pragma unroll
        for (int i = 0; i < 4; ++i)
#pragma unroll
            for (int j = 0; j < 4; ++j)
                acc[i][j] = __builtin_amdgcn_mfma_f32_16x16x32_bf16(
                    af[i], bf[j], acc[i][j], 0, 0, 0);
    }

    // epilogue: C/D layout col=lane&15, row=(lane>>4)*4+reg
#pragma unroll
    for (int i = 0; i < 4; ++i) {
        const int row = m0 + wm + i * 16 + kq * 4;
#pragma unroll
        for (int j = 0; j < 4; ++j) {
            const int col = n0 + wn + j * 16 + lm;
            float bv = HAS_BIAS ? bias[col] : 0.f;
#pragma unroll
            for (int r = 0; r < 4; ++r) {
                float v = acc[i][j][r] + bv;
                if (HAS_RES) v += resid[(size_t)(row + r) * N + col];
                if (RELU) v = fmaxf(v, 0.f);
                if (OUT_BF16)
                    ((ushort_t*)Cout)[(size_t)(row + r) * N + col] = f2bf_rne(v);
                else
                    ((float*)Cout)[(size_t)(row + r) * N + col] = v;
            }
        }
    }
}

// ---------------------------------------------------------------------------
// Flash-style tiled attention (fp32 math, bf16 output).
// One block per (b, h, 32-query tile). 256 threads = 16 (tq) x 16 (tk).
// ---------------------------------------------------------------------------
#define QT 32
#define KTT 64
#define LSTR 68

__global__ __launch_bounds__(256) void attn_tile_kernel(
    const float* __restrict__ qkv, const int* __restrict__ rel_matrix,
    const unsigned char* __restrict__ mask, const float* __restrict__ rel_A,
    ushort_t* __restrict__ attnout)
{
    __shared__ float Qs[QT * LSTR];
    __shared__ float Ks[KTT * LSTR];
    __shared__ float Vs[KTT * LSTR];
    __shared__ float Ps[QT * LSTR];
    __shared__ float r3s[QT][4];

    const int bx = blockIdx.x;
    const int qt = bx & 31;
    const int h  = (bx >> 5) % HH;
    const int b  = bx / (32 * HH);
    const int q0 = qt * QT;
    const int t  = threadIdx.x;
    const int tq = t >> 4;
    const int tk = t & 15;

    {
        const int r = t >> 3;
        const int c = (t & 7) * 8;
        const float* src = qkv + (size_t)(b * SS + q0 + r) * (3 * DD) + h * HD + c;
        float4 v0 = *(const float4*)(src);
        float4 v1 = *(const float4*)(src + 4);
        *(float4*)&Qs[r * LSTR + c]     = v0;
        *(float4*)&Qs[r * LSTR + c + 4] = v1;
    }
    __syncthreads();
    if (t < 128) {
        int q = t >> 2, c = t & 3;
        if (c < 3) {
            float s = 0.f;
            const float* a = rel_A + c * HD;
            for (int d = 0; d < HD; ++d) s += Qs[q * LSTR + d] * a[d];
            r3s[q][c] = s;
        }
    }

    float m_run[2] = {-1e30f, -1e30f};
    float l_run[2] = {0.f, 0.f};
    float oacc[2][4] = {};

    const int* relbase = rel_matrix + (size_t)b * SS * SS;
    const unsigned char* mrow = mask + (size_t)b * SS;

    for (int k0 = 0; k0 < SS; k0 += KTT) {
        __syncthreads();
        {
            const int r = t >> 2;
            const int cb = (t & 3) * 16;
            const float* kr = qkv + (size_t)(b * SS + k0 + r) * (3 * DD) + DD + h * HD + cb;
            const float* vr = kr + DD;
            float4 ka = ((const float4*)kr)[0];
            float4 kb = ((const float4*)kr)[1];
            float4 kc = ((const float4*)kr)[2];
            float4 kd = ((const float4*)kr)[3];
            float4 va = ((const float4*)vr)[0];
            float4 vb = ((const float4*)vr)[1];
            float4 vc = ((const float4*)vr)[2];
            float4 vd = ((const float4*)vr)[3];
            float* kdst = &Ks[r * LSTR + cb];
            float* vdst = &Vs[r * LSTR + cb];
            ((float4*)kdst)[0] = ka; ((float4*)kdst)[1] = kb;
            ((float4*)kdst)[2] = kc; ((float4*)kdst)[3] = kd;
            ((float4*)vdst)[0] = va; ((float4*)vdst)[1] = vb;
            ((float4*)vdst)[2] = vc; ((float4*)vdst)[3] = vd;
        }
        __syncthreads();

        float s_[2][4] = {};
#pragma unroll
        for (int d4 = 0; d4 < HD; d4 += 4) {
            float4 qa = *(const float4*)&Qs[tq * LSTR + d4];
            float4 qb = *(const float4*)&Qs[(tq + 16) * LSTR + d4];
#pragma unroll
            for (int jj = 0; jj < 4; ++jj) {
                float4 kv = *(const float4*)&Ks[(tk + 16 * jj) * LSTR + d4];
                s_[0][jj] += qa.x * kv.x + qa.y * kv.y + qa.z * kv.z + qa.w * kv.w;
                s_[1][jj] += qb.x * kv.x + qb.y * kv.y + qb.z * kv.z + qb.w * kv.w;
            }
        }

#pragma unroll
        for (int ql = 0; ql < 2; ++ql) {
            const int q = tq + 16 * ql;
            const int* relrow = relbase + (size_t)(q0 + q) * SS + k0;
#pragma unroll
            for (int jj = 0; jj < 4; ++jj) {
                const int k = tk + 16 * jj;
                int idx = relrow[k] + 1;
                float lv = (s_[ql][jj] + r3s[q][idx]) * 0.125f;
                if (mrow[k0 + k]) lv = -3e30f;
                s_[ql][jj] = lv;
            }
        }

#pragma unroll
        for (int ql = 0; ql < 2; ++ql) {
            float tm = fmaxf(fmaxf(s_[ql][0], s_[ql][1]), fmaxf(s_[ql][2], s_[ql][3]));
            tm = fmaxf(tm, __shfl_xor(tm, 1));
            tm = fmaxf(tm, __shfl_xor(tm, 2));
            tm = fmaxf(tm, __shfl_xor(tm, 4));
            tm = fmaxf(tm, __shfl_xor(tm, 8));
            float mn = fmaxf(m_run[ql], tm);
            float alpha = __expf(m_run[ql] - mn);
            m_run[ql] = mn;
            float ts = 0.f;
#pragma unroll
            for (int jj = 0; jj < 4; ++jj) {
                float p = __expf(s_[ql][jj] - mn);
                s_[ql][jj] = p;
                ts += p;
            }
            ts += __shfl_xor(ts, 1);
            ts += __shfl_xor(ts, 2);
            ts += __shfl_xor(ts, 4);
            ts += __shfl_xor(ts, 8);
            l_run[ql] = l_run[ql] * alpha + ts;
#pragma unroll
            for (int j = 0; j < 4; ++j) oacc[ql][j] *= alpha;
            const int q = tq + 16 * ql;
#pragma unroll
            for (int jj = 0; jj < 4; ++jj)
                Ps[q * LSTR + tk + 16 * jj] = s_[ql][jj];
        }
        __syncthreads();

#pragma unroll
        for (int kk = 0; kk < KTT; kk += 4) {
            float4 pa = *(const float4*)&Ps[tq * LSTR + kk];
            float4 pb = *(const float4*)&Ps[(tq + 16) * LSTR + kk];
            float pav[4] = {pa.x, pa.y, pa.z, pa.w};
            float pbv[4] = {pb.x, pb.y, pb.z, pb.w};
#pragma unroll
            for (int i = 0; i < 4; ++i) {
                float4 vv = *(const float4*)&Vs[(kk + i) * LSTR + 4 * tk];
                oacc[0][0] += pav[i] * vv.x;
                oacc[0][1] += pav[i] * vv.y;
                oacc[0][2] += pav[i] * vv.z;
                oacc[0][3] += pav[i] * vv.w;
                oacc[1][0] += pbv[i] * vv.x;
                oacc[1][1] += pbv[i] * vv.y;
                oacc[1][2] += pbv[i] * vv.z;
                oacc[1][3] += pbv[i] * vv.w;
            }
        }
    }

#pragma unroll
    for (int ql = 0; ql < 2; ++ql) {
        const int q = q0 + tq + 16 * ql;
        float inv = 1.0f / l_run[ql];
        ushort4 o;
        o.x = f2bf_rne(oacc[ql][0] * inv);
        o.y = f2bf_rne(oacc[ql][1] * inv);
        o.z = f2bf_rne(oacc[ql][2] * inv);
        o.w = f2bf_rne(oacc[ql][3] * inv);
        *(ushort4*)&attnout[(size_t)(b * SS + q) * DD + h * HD + 4 * tk] = o;
    }
}

// ---------------------------------------------------------------------------
extern "C" void kernel_launch(void* const* d_in, const int* in_sizes, int n_in,
                              void* d_out, int out_size, void* d_ws, size_t ws_size,
                              hipStream_t stream) {
    const float* inp   = (const float*)d_in[0];
    const unsigned char* amask = (const unsigned char*)d_in[1];
    const int*   relm  = (const int*)d_in[2];
    const float* qkv_w = (const float*)d_in[3];
    const float* rel_A = (const float*)d_in[4];
    const float* o_w   = (const float*)d_in[5];
    const float* w1    = (const float*)d_in[6];
    const float* b1    = (const float*)d_in[7];
    const float* w2    = (const float*)d_in[8];
    const float* b2    = (const float*)d_in[9];
    const float* ln1_g = (const float*)d_in[10];
    const float* ln1_b = (const float*)d_in[11];
    const float* ln2_g = (const float*)d_in[12];
    const float* ln2_b = (const float*)d_in[13];
    float* out = (float*)d_out;

    const int BS = BB * SS;  // 2048 rows

    // workspace layout (sizes in elements)
    char* p = (char*)d_ws;
    ushort_t* x_bf   = (ushort_t*)p; p += (size_t)BS * DD * 2;        // 3 MB
    ushort_t* att_bf = (ushort_t*)p; p += (size_t)BS * DD * 2;        // 3 MB
    ushort_t* h_bf   = (ushort_t*)p; p += (size_t)BS * DD * 2;        // 3 MB
    ushort_t* ff_bf  = (ushort_t*)p; p += (size_t)BS * DFF * 2;       // 12.6 MB
    ushort_t* qkvw_bf= (ushort_t*)p; p += (size_t)3 * DD * DD * 2;    // 3.5 MB
    ushort_t* ow_bf  = (ushort_t*)p; p += (size_t)DD * DD * 2;        // 1.2 MB
    ushort_t* w1_bf  = (ushort_t*)p; p += (size_t)DFF * DD * 2;       // 4.7 MB
    ushort_t* w2_bf  = (ushort_t*)p; p += (size_t)DD * DFF * 2;       // 4.7 MB
    float*    qkvb   = (float*)p;    p += (size_t)BS * 3 * DD * 4;    // 18.9 MB
    float*    resid  = (float*)p;    p += (size_t)BS * DD * 4;        // 6.3 MB

    // 0. weight conversions fp32 -> bf16
    {
        int n4;
        n4 = 3 * DD * DD / 4;
        cvt_bf16<<<(n4 + 255) / 256, 256, 0, stream>>>(qkv_w, qkvw_bf, n4);
        n4 = DD * DD / 4;
        cvt_bf16<<<(n4 + 255) / 256, 256, 0, stream>>>(o_w, ow_bf, n4);
        n4 = DFF * DD / 4;
        cvt_bf16<<<(n4 + 255) / 256, 256, 0, stream>>>(w1, w1_bf, n4);
        cvt_bf16<<<(n4 + 255) / 256, 256, 0, stream>>>(w2, w2_bf, n4);
    }

    // 1. LN1 -> bf16
    ln_kernel_bf<<<BS, 256, 0, stream>>>(inp, ln1_g, ln1_b, x_bf);

    // 2. QKV = x @ qkv_w.T  (fp32 out for attention)
    gemm_mfma<false, false, false, false>
        <<<dim3(3 * DD / GTN, BS / GTM), 256, 0, stream>>>(
        x_bf, qkvw_bf, nullptr, nullptr, qkvb, BS, 3 * DD, DD);

    // 3. Attention -> bf16
    attn_tile_kernel<<<BB * HH * (SS / QT), 256, 0, stream>>>(
        qkvb, relm, amask, rel_A, att_bf);

    // 4. resid = inp + att @ o_w.T  (fp32 out)
    gemm_mfma<false, false, false, true>
        <<<dim3(DD / GTN, BS / GTM), 256, 0, stream>>>(
        att_bf, ow_bf, nullptr, inp, resid, BS, DD, DD);

    // 5. LN2 -> bf16
    ln_kernel_bf<<<BS, 256, 0, stream>>>(resid, ln2_g, ln2_b, h_bf);

    // 6. ff = relu(h @ w1.T + b1) -> bf16
    gemm_mfma<true, true, true, false>
        <<<dim3(DFF / GTN, BS / GTM), 256, 0, stream>>>(
        h_bf, w1_bf, b1, nullptr, ff_bf, BS, DFF, DD);

    // 7. out = resid + ff @ w2.T + b2  (fp32 out)
    gemm_mfma<false, false, true, true>
        <<<dim3(DD / GTN, BS / GTM), 256, 0, stream>>>(
        ff_bf, w2_bf, b2, resid, out, BS, DD, DFF);
}

// Round 4
// 313.943 us; speedup vs baseline: 6.0013x; 1.4884x over previous
//
#include <hip/hip_runtime.h>
#include <hip/hip_bf16.h>

// Problem constants
#define BB 2
#define SS 1024
#define DD 768
#define HH 12
#define HD 64
#define DFF 3072
#define EPS 1e-5f

typedef unsigned short ushort_t;
typedef unsigned char uchar_t;
using short8 = __attribute__((ext_vector_type(8))) short;
using f32x4  = __attribute__((ext_vector_type(4))) float;

__device__ __forceinline__ ushort_t f2bf_rne(float f) {
    union { float f; unsigned u; } x; x.f = f;
    unsigned r = x.u + 0x7fff + ((x.u >> 16) & 1);
    return (ushort_t)(r >> 16);
}
__device__ __forceinline__ float bf2f(short u) {
    union { unsigned i; float f; } x;
    x.i = ((unsigned)(ushort_t)u) << 16;
    return x.f;
}

// ---------------------------------------------------------------------------
// fp32 -> bf16 conversion (vectorized), n4 = n/4
// ---------------------------------------------------------------------------
__global__ __launch_bounds__(256) void cvt_bf16(
    const float* __restrict__ in, ushort_t* __restrict__ out, int n4)
{
    int i = blockIdx.x * 256 + threadIdx.x;
    if (i < n4) {
        float4 v = ((const float4*)in)[i];
        ushort4 o;
        o.x = f2bf_rne(v.x); o.y = f2bf_rne(v.y);
        o.z = f2bf_rne(v.z); o.w = f2bf_rne(v.w);
        ((ushort4*)out)[i] = o;
    }
}

// ---------------------------------------------------------------------------
// Pack rel+mask into lane-permuted int8 codes:
//   codes[((b*S+q)*16 + kt)*64 + l15*4 + nt] = mask[b][k] ? 3 : rel[b][q][k]+1
//   where k = kt*64 + nt*16 + l15.
// One thread per (b,q,kt,l15); writes 4 bytes (nt=0..3) as one uint.
// ---------------------------------------------------------------------------
__global__ __launch_bounds__(256) void build_codes(
    const int* __restrict__ rel, const uchar_t* __restrict__ mask,
    unsigned* __restrict__ codes)
{
    int tid = blockIdx.x * 256 + threadIdx.x;      // B*S*16*16 total
    int l15 = tid & 15;
    int kt  = (tid >> 4) & 15;
    int q   = (tid >> 8) & (SS - 1);
    int b   = tid >> 18;
    const int* rrow = rel + ((size_t)(b * SS + q)) * SS + kt * 64 + l15;
    const uchar_t* mrow = mask + (size_t)b * SS + kt * 64 + l15;
    unsigned o = 0;
#pragma unroll
    for (int nt = 0; nt < 4; ++nt) {
        unsigned c = mrow[nt * 16] ? 3u : (unsigned)(rrow[nt * 16] + 1);
        o |= c << (8 * nt);
    }
    codes[((size_t)(b * SS + q) * 16 + kt) * 16 + l15] = o;
}

// ---------------------------------------------------------------------------
// LayerNorm: fp32 in -> bf16 out. One block per row, 256 threads, D=768.
// ---------------------------------------------------------------------------
__global__ __launch_bounds__(256) void ln_kernel_bf(
    const float* __restrict__ x, const float* __restrict__ g,
    const float* __restrict__ b, ushort_t* __restrict__ y)
{
    const int row = blockIdx.x;
    const float* xr = x + (size_t)row * DD;
    float s = 0.f, ss = 0.f;
    for (int i = threadIdx.x; i < DD; i += 256) {
        float v = xr[i];
        s += v; ss += v * v;
    }
    for (int off = 32; off; off >>= 1) {
        s  += __shfl_down(s,  off);
        ss += __shfl_down(ss, off);
    }
    __shared__ float reds[4], redss[4], bc[2];
    int t = threadIdx.x;
    if ((t & 63) == 0) { reds[t >> 6] = s; redss[t >> 6] = ss; }
    __syncthreads();
    if (t == 0) {
        float S1 = reds[0] + reds[1] + reds[2] + reds[3];
        float S2 = redss[0] + redss[1] + redss[2] + redss[3];
        float mean = S1 / DD;
        float var = S2 / DD - mean * mean;
        bc[0] = mean;
        bc[1] = rsqrtf(var + EPS);
    }
    __syncthreads();
    float mean = bc[0], inv = bc[1];
    ushort_t* yr = y + (size_t)row * DD;
    for (int i = threadIdx.x; i < DD; i += 256) {
        yr[i] = f2bf_rne((xr[i] - mean) * inv * g[i] + b[i]);
    }
}

// ---------------------------------------------------------------------------
// bf16 MFMA GEMM, register-buffered pipeline.
// C[M,N] = act( A[M,K](bf16) @ W[N,K](bf16)^T + bias + resid )
// GTM=128 rows; GTN template (128 or 64); BK=32; 256 threads = 4 waves.
// LDS chunk layout: slot = kchunk*ROWS + row (8 bf16 per slot).
// Pipeline: load tile k+1 global->VGPR overlapping compute of tile k.
// ---------------------------------------------------------------------------
#define GTM 128
#define GTK 32

template <int GTN, bool RELU, bool OUT_BF16, bool HAS_BIAS, bool HAS_RES>
__global__ __launch_bounds__(256) void gemm_mfma(
    const ushort_t* __restrict__ A, const ushort_t* __restrict__ W,
    const float* __restrict__ bias, const float* __restrict__ resid,
    void* __restrict__ Cout, int M, int N, int K)
{
    constexpr int MI = (GTN == 128) ? 4 : 2;   // m-tiles per wave
    __shared__ __align__(16) ushort_t As[512 * 8];                 // 8 KB
    __shared__ __align__(16) ushort_t Bs[(GTN == 128 ? 512 : 256) * 8];

    const int t  = threadIdx.x;
    const int m0 = blockIdx.y * GTM;
    const int n0 = blockIdx.x * GTN;
    const int w  = t >> 6;
    const int l  = t & 63;
    const int wm = (GTN == 128) ? (w >> 1) * 64 : w * 32;
    const int wn = (GTN == 128) ? (w & 1) * 64 : 0;
    const int lm = l & 15;
    const int kq = l >> 4;           // k-chunk 0..3

    // A staging addresses: thread covers slots t (chunk t>>7) and t+256 (chunk +2)
    const ushort_t* gA0 = A + (size_t)(m0 + (t & 127)) * K + (t >> 7) * 8;
    const ushort_t* gA1 = gA0 + 16;
    // B staging
    const ushort_t* gB0;
    const ushort_t* gB1 = nullptr;
    if (GTN == 128) {
        gB0 = W + (size_t)(n0 + (t & 127)) * K + (t >> 7) * 8;
        gB1 = gB0 + 16;
    } else {
        gB0 = W + (size_t)(n0 + (t & 63)) * K + (t >> 6) * 8;
    }

    const ushort_t* aptr = &As[(size_t)(kq * 128 + wm + lm) * 8];
    const ushort_t* bptr = &Bs[(size_t)(kq * (GTN == 128 ? 128 : 64) + wn + lm) * 8];

    f32x4 acc[MI][4] = {};

    short8 na0 = *(const short8*)gA0;
    short8 na1 = *(const short8*)gA1;
    short8 nb0 = *(const short8*)gB0;
    short8 nb1;
    if (GTN == 128) nb1 = *(const short8*)gB1;

    for (int k0 = 0; k0 < K; k0 += GTK) {
        __syncthreads();
        *(short8*)&As[(size_t)t * 8]         = na0;
        *(short8*)&As[(size_t)(t + 256) * 8] = na1;
        *(short8*)&Bs[(size_t)t * 8]         = nb0;
        if (GTN == 128) *(short8*)&Bs[(size_t)(t + 256) * 8] = nb1;
        __syncthreads();

        if (k0 + GTK < K) {
            na0 = *(const short8*)(gA0 + k0 + GTK);
            na1 = *(const short8*)(gA1 + k0 + GTK);
            nb0 = *(const short8*)(gB0 + k0 + GTK);
            if (GTN == 128) nb1 = *(const short8*)(gB1 + k0 + GTK);
        }

        short8 af[MI], bf[4];
#pragma unroll
        for (int i = 0; i < MI; ++i)
            af[i] = *(const short8*)(aptr + (size_t)i * 16 * 8);
#pragma unroll
        for (int j = 0; j < 4; ++j)
            bf[j] = *(const short8*)(bptr + (size_t)j * 16 * 8);
#pragma unroll
        for (int i = 0; i < MI; ++i)
#pragma unroll
            for (int j = 0; j < 4; ++j)
                acc[i][j] = __builtin_amdgcn_mfma_f32_16x16x32_bf16(
                    af[i], bf[j], acc[i][j], 0, 0, 0);
    }

    // epilogue: C/D layout col=lane&15, row=(lane>>4)*4+reg
#pragma unroll
    for (int i = 0; i < MI; ++i) {
        const int row = m0 + wm + i * 16 + kq * 4;
#pragma unroll
        for (int j = 0; j < 4; ++j) {
            const int col = n0 + wn + j * 16 + lm;
            float bv = HAS_BIAS ? bias[col] : 0.f;
#pragma unroll
            for (int r = 0; r < 4; ++r) {
                float v = acc[i][j][r] + bv;
                if (HAS_RES) v += resid[(size_t)(row + r) * N + col];
                if (RELU) v = fmaxf(v, 0.f);
                if (OUT_BF16)
                    ((ushort_t*)Cout)[(size_t)(row + r) * N + col] = f2bf_rne(v);
                else
                    ((float*)Cout)[(size_t)(row + r) * N + col] = v;
            }
        }
    }
}

// ---------------------------------------------------------------------------
// MFMA flash attention. Block per (b, h, 64-query tile); 256 threads = 4
// waves; wave w owns q rows [w*16, w*16+16). All matmuls on
// mfma_f32_16x16x32_bf16. K tile staged via XOR-swizzled global_load_lds;
// V tile transposed into LDS as bf16 pairs (kpair XOR-swizzled); P goes
// C-layout -> LDS -> A-layout (per-wave region, no barrier needed).
// Softmax state register-resident: rows = quad*4+reg, reduced via shfl_xor.
// ---------------------------------------------------------------------------
__global__ __launch_bounds__(256) void attn_mfma_kernel(
    const ushort_t* __restrict__ qkv,      // (B*S, 2304) bf16
    const unsigned* __restrict__ codes,    // packed rel/mask codes
    const float* __restrict__ rel_A,       // (3, 64) fp32
    ushort_t* __restrict__ attnout)        // (B*S, 768) bf16
{
    __shared__ __align__(16) ushort_t Ks[64 * 64];     // swizzled chunks, 8 KB
    __shared__ __align__(16) unsigned Vt2[64 * 36];    // d-major kpairs, 9 KB
    __shared__ __align__(16) ushort_t Ps[64 * 72];     // per-wave P, 9 KB
    __shared__ __align__(16) float r3s[64][4];

    const int bx = blockIdx.x;
    const int qt = bx & 15;
    const int h  = (bx >> 4) % HH;
    const int b  = bx / (16 * HH);
    const int q0 = qt * 64;
    const int t  = threadIdx.x;
    const int w  = t >> 6;
    const int l  = t & 63;
    const int l15  = l & 15;
    const int quad = l >> 4;

    // ---- Q fragments (A-layout direct from global): row = w*16 + l15 ----
    const size_t qrow = (size_t)(b * SS + q0 + w * 16 + l15) * (3 * DD) + h * HD;
    const short8 qf0 = *(const short8*)(qkv + qrow + quad * 8);
    const short8 qf1 = *(const short8*)(qkv + qrow + 32 + quad * 8);

    // ---- r3[q][c] = q . rel_A[c], via in-register partial + shfl reduce ----
    {
        float rv[3];
#pragma unroll
        for (int c = 0; c < 3; ++c) {
            const float* a = rel_A + c * HD + quad * 8;
            float acc = 0.f;
#pragma unroll
            for (int j = 0; j < 8; ++j) acc += bf2f(qf0[j]) * a[j];
#pragma unroll
            for (int j = 0; j < 8; ++j) acc += bf2f(qf1[j]) * a[32 + j];
            acc += __shfl_xor(acc, 16);
            acc += __shfl_xor(acc, 32);
            rv[c] = acc;
        }
        if (quad == 0) {
            float4 f4 = make_float4(rv[0], rv[1], rv[2], -2.4e31f);
            *(float4*)&r3s[w * 16 + l15][0] = f4;
        }
    }
    __syncthreads();
    float4 r3v[4];
#pragma unroll
    for (int reg = 0; reg < 4; ++reg)
        r3v[reg] = *(const float4*)&r3s[w * 16 + quad * 4 + reg][0];

    float m_run[4] = {-1e30f, -1e30f, -1e30f, -1e30f};
    float l_run[4] = {0.f, 0.f, 0.f, 0.f};
    f32x4 oacc[4] = {};

    for (int kt = 0; kt < SS / 64; ++kt) {
        const int k0 = kt * 64;
        __syncthreads();
        // ---- stage K (XOR-swizzled chunks): slot = r*8 + cphys ----
        {
            const int r  = t >> 3;
            const int cp = t & 7;
            const int cl  = cp ^ (r & 7);
            const ushort_t* g = qkv + (size_t)(b * SS + k0 + r) * (3 * DD) + DD + h * HD + cl * 8;
            __builtin_amdgcn_global_load_lds(
                (const __attribute__((address_space(1))) unsigned*)g,
                (__attribute__((address_space(3))) unsigned*)(Ks + (size_t)t * 8), 16, 0, 0);
            const int r2  = r + 32;
            const int cl2 = cp ^ (r2 & 7);
            const ushort_t* g2 = qkv + (size_t)(b * SS + k0 + r2) * (3 * DD) + DD + h * HD + cl2 * 8;
            __builtin_amdgcn_global_load_lds(
                (const __attribute__((address_space(1))) unsigned*)g2,
                (__attribute__((address_space(3))) unsigned*)(Ks + (size_t)(t + 256) * 8), 16, 0, 0);
        }
        // ---- stage V transposed: Vt2[d][kp'] = (V[2kp][d], V[2kp+1][d]) ----
        {
            const int kp = t >> 3;          // 0..31
            const int dg = t & 7;           // d-group of 8
            const ushort_t* g = qkv + (size_t)(b * SS + k0 + 2 * kp) * (3 * DD) + 2 * DD + h * HD + dg * 8;
            short8 va = *(const short8*)g;
            short8 vb = *(const short8*)(g + 3 * DD);
            const int kps = kp ^ ((dg & 7) * 4);
#pragma unroll
            for (int i = 0; i < 8; ++i)
                Vt2[(size_t)(dg * 8 + i) * 36 + kps] =
                    (unsigned)(ushort_t)va[i] | ((unsigned)(ushort_t)vb[i] << 16);
        }
        __syncthreads();

        // ---- S = Q K^T : 4 n-tiles x 2 k-chunks of MFMA ----
        f32x4 sacc[4] = {};
#pragma unroll
        for (int kc = 0; kc < 2; ++kc) {
            const short8 qv = kc ? qf1 : qf0;
#pragma unroll
            for (int nt = 0; nt < 4; ++nt) {
                const int row = nt * 16 + l15;
                const int cp  = (kc * 4 + quad) ^ (row & 7);
                const short8 kf = *(const short8*)(Ks + (size_t)row * 64 + cp * 8);
                sacc[nt] = __builtin_amdgcn_mfma_f32_16x16x32_bf16(qv, kf, sacc[nt], 0, 0, 0);
            }
        }

        // ---- rel/mask + online softmax (per reg-row) ----
        float alpha[4];
#pragma unroll
        for (int reg = 0; reg < 4; ++reg) {
            const int qloc = w * 16 + quad * 4 + reg;
            const unsigned cds = codes[((size_t)(b * SS + q0 + qloc) * 16 + kt) * 16 + l15];
            float lv[4];
#pragma unroll
            for (int nt = 0; nt < 4; ++nt) {
                const unsigned c = (cds >> (8 * nt)) & 0xff;
                const float4 r4 = r3v[reg];
                float rvv = (c == 0) ? r4.x : (c == 1) ? r4.y : (c == 2) ? r4.z : r4.w;
                lv[nt] = (sacc[nt][reg] + rvv) * 0.125f;
            }
            float tm = fmaxf(fmaxf(lv[0], lv[1]), fmaxf(lv[2], lv[3]));
            tm = fmaxf(tm, __shfl_xor(tm, 1));
            tm = fmaxf(tm, __shfl_xor(tm, 2));
            tm = fmaxf(tm, __shfl_xor(tm, 4));
            tm = fmaxf(tm, __shfl_xor(tm, 8));
            const float mn = fmaxf(m_run[reg], tm);
            alpha[reg] = __expf(m_run[reg] - mn);
            m_run[reg] = mn;
            float ts = 0.f;
#pragma unroll
            for (int nt = 0; nt < 4; ++nt) {
                const float p = __expf(lv[nt] - mn);
                ts += p;
                Ps[(size_t)qloc * 72 + nt * 16 + l15] = f2bf_rne(p);
            }
            ts += __shfl_xor(ts, 1);
            ts += __shfl_xor(ts, 2);
            ts += __shfl_xor(ts, 4);
            ts += __shfl_xor(ts, 8);
            l_run[reg] = l_run[reg] * alpha[reg] + ts;
        }
        // rescale O by alpha (row = quad*4+reg matches C layout)
#pragma unroll
        for (int dt = 0; dt < 4; ++dt)
#pragma unroll
            for (int reg = 0; reg < 4; ++reg)
                oacc[dt][reg] *= alpha[reg];

        // ---- O += P V  (P per-wave in LDS; same-wave, no barrier) ----
#pragma unroll
        for (int kc = 0; kc < 2; ++kc) {
            const short8 pf = *(const short8*)(Ps + (size_t)(w * 16 + l15) * 72 + kc * 32 + quad * 8);
#pragma unroll
            for (int dt = 0; dt < 4; ++dt) {
                const int d  = dt * 16 + l15;
                const int dg = d >> 3;
                const int kps0 = (kc * 16 + quad * 4) ^ ((dg & 7) * 4);
                const short8 vf = *(const short8*)((const ushort_t*)&Vt2[(size_t)d * 36 + kps0]);
                oacc[dt] = __builtin_amdgcn_mfma_f32_16x16x32_bf16(pf, vf, oacc[dt], 0, 0, 0);
            }
        }
    }

    // ---- epilogue: O / l ----
#pragma unroll
    for (int reg = 0; reg < 4; ++reg) {
        const float inv = 1.0f / l_run[reg];
        const size_t orow = (size_t)(b * SS + q0 + w * 16 + quad * 4 + reg) * DD + h * HD;
#pragma unroll
        for (int dt = 0; dt < 4; ++dt)
            attnout[orow + dt * 16 + l15] = f2bf_rne(oacc[dt][reg] * inv);
    }
}

// ---------------------------------------------------------------------------
extern "C" void kernel_launch(void* const* d_in, const int* in_sizes, int n_in,
                              void* d_out, int out_size, void* d_ws, size_t ws_size,
                              hipStream_t stream) {
    const float* inp   = (const float*)d_in[0];
    const uchar_t* amask = (const uchar_t*)d_in[1];
    const int*   relm  = (const int*)d_in[2];
    const float* qkv_w = (const float*)d_in[3];
    const float* rel_A = (const float*)d_in[4];
    const float* o_w   = (const float*)d_in[5];
    const float* w1    = (const float*)d_in[6];
    const float* b1    = (const float*)d_in[7];
    const float* w2    = (const float*)d_in[8];
    const float* b2    = (const float*)d_in[9];
    const float* ln1_g = (const float*)d_in[10];
    const float* ln1_b = (const float*)d_in[11];
    const float* ln2_g = (const float*)d_in[12];
    const float* ln2_b = (const float*)d_in[13];
    float* out = (float*)d_out;

    const int BS = BB * SS;  // 2048 rows

    // workspace layout
    char* p = (char*)d_ws;
    ushort_t* x_bf   = (ushort_t*)p; p += (size_t)BS * DD * 2;
    ushort_t* att_bf = (ushort_t*)p; p += (size_t)BS * DD * 2;
    ushort_t* h_bf   = (ushort_t*)p; p += (size_t)BS * DD * 2;
    ushort_t* ff_bf  = (ushort_t*)p; p += (size_t)BS * DFF * 2;
    ushort_t* qkvw_bf= (ushort_t*)p; p += (size_t)3 * DD * DD * 2;
    ushort_t* ow_bf  = (ushort_t*)p; p += (size_t)DD * DD * 2;
    ushort_t* w1_bf  = (ushort_t*)p; p += (size_t)DFF * DD * 2;
    ushort_t* w2_bf  = (ushort_t*)p; p += (size_t)DD * DFF * 2;
    ushort_t* qkv_bf = (ushort_t*)p; p += (size_t)BS * 3 * DD * 2;
    float*    resid  = (float*)p;    p += (size_t)BS * DD * 4;
    unsigned* codes  = (unsigned*)p; p += (size_t)BB * SS * SS;   // 2 MB

    // 0. weight conversions fp32 -> bf16 + code packing
    {
        int n4;
        n4 = 3 * DD * DD / 4;
        cvt_bf16<<<(n4 + 255) / 256, 256, 0, stream>>>(qkv_w, qkvw_bf, n4);
        n4 = DD * DD / 4;
        cvt_bf16<<<(n4 + 255) / 256, 256, 0, stream>>>(o_w, ow_bf, n4);
        n4 = DFF * DD / 4;
        cvt_bf16<<<(n4 + 255) / 256, 256, 0, stream>>>(w1, w1_bf, n4);
        cvt_bf16<<<(n4 + 255) / 256, 256, 0, stream>>>(w2, w2_bf, n4);
        build_codes<<<(BB * SS * 256) / 256, 256, 0, stream>>>(relm, amask, codes);
    }

    // 1. LN1 -> bf16
    ln_kernel_bf<<<BS, 256, 0, stream>>>(inp, ln1_g, ln1_b, x_bf);

    // 2. QKV = x @ qkv_w.T -> bf16
    gemm_mfma<128, false, true, false, false>
        <<<dim3(3 * DD / 128, BS / GTM), 256, 0, stream>>>(
        x_bf, qkvw_bf, nullptr, nullptr, qkv_bf, BS, 3 * DD, DD);

    // 3. MFMA flash attention -> bf16 : grid = B*H*(S/64) = 384
    attn_mfma_kernel<<<BB * HH * (SS / 64), 256, 0, stream>>>(
        qkv_bf, codes, rel_A, att_bf);

    // 4. resid = inp + att @ o_w.T  (fp32 out), N=768 -> GTN=64
    gemm_mfma<64, false, false, false, true>
        <<<dim3(DD / 64, BS / GTM), 256, 0, stream>>>(
        att_bf, ow_bf, nullptr, inp, resid, BS, DD, DD);

    // 5. LN2 -> bf16
    ln_kernel_bf<<<BS, 256, 0, stream>>>(resid, ln2_g, ln2_b, h_bf);

    // 6. ff = relu(h @ w1.T + b1) -> bf16
    gemm_mfma<128, true, true, true, false>
        <<<dim3(DFF / 128, BS / GTM), 256, 0, stream>>>(
        h_bf, w1_bf, b1, nullptr, ff_bf, BS, DFF, DD);

    // 7. out = resid + ff @ w2.T + b2  (fp32 out), N=768 -> GTN=64
    gemm_mfma<64, false, false, true, true>
        <<<dim3(DD / 64, BS / GTM), 256, 0, stream>>>(
        ff_bf, w2_bf, b2, resid, out, BS, DD, DFF);
}